// Round 6
// baseline (82.318 us; speedup 1.0000x reference)
//
#include <hip/hip_runtime.h>
#include <hip/hip_bf16.h>

#define EPS_F 1e-8f
#define MIN_THRESH_F 0.1f

// Single compute kernel + tiny memset node (counters), no second kernel.
// Gather: one row per HALF-wave (32 lanes x 4 float4 = 512 floats = D).
// Completion: two-level counters (64 groups of 32 blocks -> 1 global) to
// avoid R1's same-address atomic burst (2048 same-addr atomics ~= 48us).
// Last block reduces the 2048 partials in-kernel (L2-warm).
//
// ws layout: [0, 16 KB)  float2 partials[2048]
//            [16 KB, +65*128 B) padded uint counters (zeroed each call)

#define NBLOCKS 2048
#define CNT_STRIDE_U32 32            // 128 B between counters (no line sharing)

__global__ __launch_bounds__(256) void cosloss_fused(
    const float* __restrict__ a, const float* __restrict__ b,
    const int* __restrict__ labels, int N,
    float2* __restrict__ partials, unsigned int* __restrict__ counters,
    float* __restrict__ out)
{
    const int lane = threadIdx.x & 63;
    const int wave = threadIdx.x >> 6;      // 0..3
    const int sub  = lane & 31;             // lane within half-wave
    const int half = lane >> 5;             // 0 or 1
    const int hwid = (blockIdx.x << 3) + (wave << 1) + half;  // half-wave id
    const int nhw  = gridDim.x << 3;        // 16384 half-waves

    float total = 0.0f, cnt = 0.0f;

    for (int r = hwid; r < N; r += nhw) {   // trip count 1 for N=16384
        const int label = labels[r];
        const char* pa = (const char*)a + ((long long)label << 11) + (sub << 4);
        const char* pb = (const char*)b + ((long long)label << 11) + (sub << 4);

        float4 A0 = *(const float4*)(pa);
        float4 A1 = *(const float4*)(pa + 512);
        float4 A2 = *(const float4*)(pa + 1024);
        float4 A3 = *(const float4*)(pa + 1536);
        float4 B0 = *(const float4*)(pb);
        float4 B1 = *(const float4*)(pb + 512);
        float4 B2 = *(const float4*)(pb + 1024);
        float4 B3 = *(const float4*)(pb + 1536);

        // keep all 8 loads in flight before any FMA (distinct dest regs)
        asm volatile("" ::
            "v"(A0.x), "v"(A0.w), "v"(A1.x), "v"(A1.w),
            "v"(A2.x), "v"(A2.w), "v"(A3.x), "v"(A3.w),
            "v"(B0.x), "v"(B0.w), "v"(B1.x), "v"(B1.w),
            "v"(B2.x), "v"(B2.w), "v"(B3.x), "v"(B3.w));

        float ip = A0.x*B0.x + A0.y*B0.y + A0.z*B0.z + A0.w*B0.w
                 + A1.x*B1.x + A1.y*B1.y + A1.z*B1.z + A1.w*B1.w
                 + A2.x*B2.x + A2.y*B2.y + A2.z*B2.z + A2.w*B2.w
                 + A3.x*B3.x + A3.y*B3.y + A3.z*B3.z + A3.w*B3.w;
        float s1 = A0.x*A0.x + A0.y*A0.y + A0.z*A0.z + A0.w*A0.w
                 + A1.x*A1.x + A1.y*A1.y + A1.z*A1.z + A1.w*A1.w
                 + A2.x*A2.x + A2.y*A2.y + A2.z*A2.z + A2.w*A2.w
                 + A3.x*A3.x + A3.y*A3.y + A3.z*A3.z + A3.w*A3.w;
        float s2 = B0.x*B0.x + B0.y*B0.y + B0.z*B0.z + B0.w*B0.w
                 + B1.x*B1.x + B1.y*B1.y + B1.z*B1.z + B1.w*B1.w
                 + B2.x*B2.x + B2.y*B2.y + B2.z*B2.z + B2.w*B2.w
                 + B3.x*B3.x + B3.y*B3.y + B3.z*B3.z + B3.w*B3.w;

        #pragma unroll
        for (int off = 16; off >= 1; off >>= 1) {
            ip += __shfl_xor(ip, off);
            s1 += __shfl_xor(s1, off);
            s2 += __shfl_xor(s2, off);
        }

        if (sub == 0) {
            float c = ip / fmaxf(sqrtf(s1) * sqrtf(s2), EPS_F);
            if (c >= MIN_THRESH_F) { total += c; cnt += 1.0f; }
        }
    }

    // block reduce -> partial, then two-level completion detection
    __shared__ float st[8], sc[8];
    __shared__ int isLast;
    if (sub == 0) { st[(wave << 1) + half] = total; sc[(wave << 1) + half] = cnt; }
    __syncthreads();
    if (threadIdx.x == 0) {
        float t = 0.0f, c = 0.0f;
        #pragma unroll
        for (int i = 0; i < 8; ++i) { t += st[i]; c += sc[i]; }
        partials[blockIdx.x] = make_float2(t, c);
        __threadfence();  // partial visible device-wide before the atomics
        int last = 0;
        // group = blockIdx>>5 : 64 groups of 32 blocks; padded counters
        if (atomicAdd(&counters[(blockIdx.x >> 5) * CNT_STRIDE_U32], 1u) == 31u) {
            if (atomicAdd(&counters[64 * CNT_STRIDE_U32], 1u) == 63u) last = 1;
        }
        isLast = last;
    }
    __syncthreads();

    if (isLast) {
        __threadfence();  // acquire: all partials now visible
        const float4* p4 = (const float4*)partials;   // 1024 float4
        float t = 0.0f, c = 0.0f;
        #pragma unroll
        for (int k = 0; k < 4; ++k) {
            float4 p = p4[threadIdx.x + (k << 8)];
            t += p.x + p.z;
            c += p.y + p.w;
        }
        #pragma unroll
        for (int off = 32; off >= 1; off >>= 1) {
            t += __shfl_xor(t, off);
            c += __shfl_xor(c, off);
        }
        __shared__ float ft[4], fc[4];
        if (lane == 0) { ft[wave] = t; fc[wave] = c; }
        __syncthreads();
        if (threadIdx.x == 0) {
            float T = ft[0] + ft[1] + ft[2] + ft[3];
            float C = fc[0] + fc[1] + fc[2] + fc[3];
            if (C < 1.0f) C = 1.0f;
            out[0] = T / C;
        }
    }
}

extern "C" void kernel_launch(void* const* d_in, const int* in_sizes, int n_in,
                              void* d_out, int out_size, void* d_ws, size_t ws_size,
                              hipStream_t stream)
{
    const float* a      = (const float*)d_in[0];
    const float* b      = (const float*)d_in[1];
    const int*   labels = (const int*)d_in[2];
    const int N = in_sizes[2];

    unsigned char* ws = (unsigned char*)d_ws;
    float2*       partials = (float2*)ws;
    unsigned int* counters = (unsigned int*)(ws + NBLOCKS * sizeof(float2));

    // zero the 65 padded counters (8.3 KB) -- graph-capture legal
    hipMemsetAsync(counters, 0, 65 * CNT_STRIDE_U32 * sizeof(unsigned int), stream);

    cosloss_fused<<<NBLOCKS, 256, 0, stream>>>(a, b, labels, N,
                                               partials, counters, (float*)d_out);
}

// Round 7
// 18.389 us; speedup vs baseline: 4.4764x; 4.4764x over previous
//
#include <hip/hip_runtime.h>
#include <hip/hip_bf16.h>

#define EPS_F 1e-8f
#define MIN_THRESH_F 0.1f

// Two kernels. In-kernel cross-block completion is ruled out on MI355X:
// R4 grid.sync = 141us, R6 threadfence+atomic last-block = 82us (2048
// device-scope release fences force per-XCD L2 writebacks).
// Gather: one row per HALF-wave (32 lanes x 4 float4 = 512 floats = D).
// 1024 blocks x 512 threads = 8192 waves = 100% occupancy, half the
// dispatched blocks and half the partials vs the 2048x256 variant.
// d_ws: float2 partials[1024], written unconditionally -> deterministic,
// no memset, no atomics.

__global__ __launch_bounds__(512) void cosloss_main(
    const float* __restrict__ a, const float* __restrict__ b,
    const int* __restrict__ labels, int N, float2* __restrict__ partials)
{
    const int lane = threadIdx.x & 63;
    const int wave = threadIdx.x >> 6;      // 0..7
    const int sub  = lane & 31;             // lane within half-wave
    const int half = lane >> 5;             // 0 or 1
    const int hwid = (blockIdx.x << 4) + (wave << 1) + half;  // half-wave id
    const int nhw  = gridDim.x << 4;        // 16384 half-waves

    float total = 0.0f, cnt = 0.0f;

    for (int r = hwid; r < N; r += nhw) {   // trip count 1 for N=16384
        const int label = labels[r];
        const char* pa = (const char*)a + ((long long)label << 11) + (sub << 4);
        const char* pb = (const char*)b + ((long long)label << 11) + (sub << 4);

        float4 A0 = *(const float4*)(pa);
        float4 A1 = *(const float4*)(pa + 512);
        float4 A2 = *(const float4*)(pa + 1024);
        float4 A3 = *(const float4*)(pa + 1536);
        float4 B0 = *(const float4*)(pb);
        float4 B1 = *(const float4*)(pb + 512);
        float4 B2 = *(const float4*)(pb + 1024);
        float4 B3 = *(const float4*)(pb + 1536);

        // keep all 8 loads in flight before any FMA (distinct dest regs)
        asm volatile("" ::
            "v"(A0.x), "v"(A0.w), "v"(A1.x), "v"(A1.w),
            "v"(A2.x), "v"(A2.w), "v"(A3.x), "v"(A3.w),
            "v"(B0.x), "v"(B0.w), "v"(B1.x), "v"(B1.w),
            "v"(B2.x), "v"(B2.w), "v"(B3.x), "v"(B3.w));

        float ip = A0.x*B0.x + A0.y*B0.y + A0.z*B0.z + A0.w*B0.w
                 + A1.x*B1.x + A1.y*B1.y + A1.z*B1.z + A1.w*B1.w
                 + A2.x*B2.x + A2.y*B2.y + A2.z*B2.z + A2.w*B2.w
                 + A3.x*B3.x + A3.y*B3.y + A3.z*B3.z + A3.w*B3.w;
        float s1 = A0.x*A0.x + A0.y*A0.y + A0.z*A0.z + A0.w*A0.w
                 + A1.x*A1.x + A1.y*A1.y + A1.z*A1.z + A1.w*A1.w
                 + A2.x*A2.x + A2.y*A2.y + A2.z*A2.z + A2.w*A2.w
                 + A3.x*A3.x + A3.y*A3.y + A3.z*A3.z + A3.w*A3.w;
        float s2 = B0.x*B0.x + B0.y*B0.y + B0.z*B0.z + B0.w*B0.w
                 + B1.x*B1.x + B1.y*B1.y + B1.z*B1.z + B1.w*B1.w
                 + B2.x*B2.x + B2.y*B2.y + B2.z*B2.z + B2.w*B2.w
                 + B3.x*B3.x + B3.y*B3.y + B3.z*B3.z + B3.w*B3.w;

        // 5-step butterfly within the 32-lane half
        #pragma unroll
        for (int off = 16; off >= 1; off >>= 1) {
            ip += __shfl_xor(ip, off);
            s1 += __shfl_xor(s1, off);
            s2 += __shfl_xor(s2, off);
        }

        if (sub == 0) {
            float c = ip / fmaxf(sqrtf(s1) * sqrtf(s2), EPS_F);
            if (c >= MIN_THRESH_F) { total += c; cnt += 1.0f; }
        }
    }

    __shared__ float st[16], sc[16];
    if (sub == 0) { st[(wave << 1) + half] = total; sc[(wave << 1) + half] = cnt; }
    __syncthreads();
    if (threadIdx.x == 0) {
        float t = 0.0f, c = 0.0f;
        #pragma unroll
        for (int i = 0; i < 16; ++i) { t += st[i]; c += sc[i]; }
        partials[blockIdx.x] = make_float2(t, c);
    }
}

__global__ __launch_bounds__(256) void cosloss_final(
    const float4* __restrict__ partials4, float* __restrict__ out)
{
    // 1024 float2 partials = 512 float4; 256 threads x 2
    float t = 0.0f, c = 0.0f;
    #pragma unroll
    for (int k = 0; k < 2; ++k) {
        float4 p = partials4[threadIdx.x + (k << 8)];
        t += p.x + p.z;
        c += p.y + p.w;
    }
    #pragma unroll
    for (int off = 32; off >= 1; off >>= 1) {
        t += __shfl_xor(t, off);
        c += __shfl_xor(c, off);
    }
    __shared__ float st[4], sc[4];
    const int lane = threadIdx.x & 63, w = threadIdx.x >> 6;
    if (lane == 0) { st[w] = t; sc[w] = c; }
    __syncthreads();
    if (threadIdx.x == 0) {
        float T = st[0] + st[1] + st[2] + st[3];
        float C = sc[0] + sc[1] + sc[2] + sc[3];
        if (C < 1.0f) C = 1.0f;
        out[0] = T / C;
    }
}

extern "C" void kernel_launch(void* const* d_in, const int* in_sizes, int n_in,
                              void* d_out, int out_size, void* d_ws, size_t ws_size,
                              hipStream_t stream)
{
    const float* a      = (const float*)d_in[0];
    const float* b      = (const float*)d_in[1];
    const int*   labels = (const int*)d_in[2];
    const int N = in_sizes[2];

    float2* partials = (float2*)d_ws;

    cosloss_main<<<1024, 512, 0, stream>>>(a, b, labels, N, partials);
    cosloss_final<<<1, 256, 0, stream>>>((const float4*)partials, (float*)d_out);
}

// Round 8
// 17.853 us; speedup vs baseline: 4.6109x; 1.0300x over previous
//
#include <hip/hip_runtime.h>
#include <hip/hip_bf16.h>

#define EPS_F 1e-8f
#define MIN_THRESH_F 0.1f

// Two kernels. In-kernel cross-block completion is ruled out on MI355X:
// R4 grid.sync = 141us, R6 threadfence+atomic last-block = 82us (device-
// scope release fences force per-XCD L2 writebacks). Same-address atomic
// burst ruled out in R1 (+48us).
// Gather: one row per HALF-wave (32 lanes x 4 float4 = 512 floats = D).
// 1024 blocks x 512 threads = 8192 waves = 100% occupancy.
// Finalize: ONE 64-lane wave, no LDS, no syncthreads (8 float4 per lane).
// d_ws: float2 partials[1024], written unconditionally -> deterministic,
// no memset, no atomics.

__global__ __launch_bounds__(512) void cosloss_main(
    const float* __restrict__ a, const float* __restrict__ b,
    const int* __restrict__ labels, int N, float2* __restrict__ partials)
{
    const int lane = threadIdx.x & 63;
    const int wave = threadIdx.x >> 6;      // 0..7
    const int sub  = lane & 31;             // lane within half-wave
    const int half = lane >> 5;             // 0 or 1
    const int hwid = (blockIdx.x << 4) + (wave << 1) + half;  // half-wave id
    const int nhw  = gridDim.x << 4;        // 16384 half-waves

    float total = 0.0f, cnt = 0.0f;

    for (int r = hwid; r < N; r += nhw) {   // trip count 1 for N=16384
        const int label = labels[r];
        const char* pa = (const char*)a + ((long long)label << 11) + (sub << 4);
        const char* pb = (const char*)b + ((long long)label << 11) + (sub << 4);

        float4 A0 = *(const float4*)(pa);
        float4 A1 = *(const float4*)(pa + 512);
        float4 A2 = *(const float4*)(pa + 1024);
        float4 A3 = *(const float4*)(pa + 1536);
        float4 B0 = *(const float4*)(pb);
        float4 B1 = *(const float4*)(pb + 512);
        float4 B2 = *(const float4*)(pb + 1024);
        float4 B3 = *(const float4*)(pb + 1536);

        // keep all 8 loads in flight before any FMA (distinct dest regs)
        asm volatile("" ::
            "v"(A0.x), "v"(A0.w), "v"(A1.x), "v"(A1.w),
            "v"(A2.x), "v"(A2.w), "v"(A3.x), "v"(A3.w),
            "v"(B0.x), "v"(B0.w), "v"(B1.x), "v"(B1.w),
            "v"(B2.x), "v"(B2.w), "v"(B3.x), "v"(B3.w));

        float ip = A0.x*B0.x + A0.y*B0.y + A0.z*B0.z + A0.w*B0.w
                 + A1.x*B1.x + A1.y*B1.y + A1.z*B1.z + A1.w*B1.w
                 + A2.x*B2.x + A2.y*B2.y + A2.z*B2.z + A2.w*B2.w
                 + A3.x*B3.x + A3.y*B3.y + A3.z*B3.z + A3.w*B3.w;
        float s1 = A0.x*A0.x + A0.y*A0.y + A0.z*A0.z + A0.w*A0.w
                 + A1.x*A1.x + A1.y*A1.y + A1.z*A1.z + A1.w*A1.w
                 + A2.x*A2.x + A2.y*A2.y + A2.z*A2.z + A2.w*A2.w
                 + A3.x*A3.x + A3.y*A3.y + A3.z*A3.z + A3.w*A3.w;
        float s2 = B0.x*B0.x + B0.y*B0.y + B0.z*B0.z + B0.w*B0.w
                 + B1.x*B1.x + B1.y*B1.y + B1.z*B1.z + B1.w*B1.w
                 + B2.x*B2.x + B2.y*B2.y + B2.z*B2.z + B2.w*B2.w
                 + B3.x*B3.x + B3.y*B3.y + B3.z*B3.z + B3.w*B3.w;

        // 5-step butterfly within the 32-lane half
        #pragma unroll
        for (int off = 16; off >= 1; off >>= 1) {
            ip += __shfl_xor(ip, off);
            s1 += __shfl_xor(s1, off);
            s2 += __shfl_xor(s2, off);
        }

        if (sub == 0) {
            float c = ip / fmaxf(sqrtf(s1) * sqrtf(s2), EPS_F);
            if (c >= MIN_THRESH_F) { total += c; cnt += 1.0f; }
        }
    }

    __shared__ float st[16], sc[16];
    if (sub == 0) { st[(wave << 1) + half] = total; sc[(wave << 1) + half] = cnt; }
    __syncthreads();
    if (threadIdx.x == 0) {
        float t = 0.0f, c = 0.0f;
        #pragma unroll
        for (int i = 0; i < 16; ++i) { t += st[i]; c += sc[i]; }
        partials[blockIdx.x] = make_float2(t, c);
    }
}

__global__ __launch_bounds__(64) void cosloss_final(
    const float4* __restrict__ partials4, float* __restrict__ out)
{
    // 1024 float2 partials = 512 float4; one wave, 8 float4 per lane.
    const int lane = threadIdx.x;
    float t = 0.0f, c = 0.0f;
    #pragma unroll
    for (int k = 0; k < 8; ++k) {
        float4 p = partials4[lane + (k << 6)];
        t += p.x + p.z;
        c += p.y + p.w;
    }
    #pragma unroll
    for (int off = 32; off >= 1; off >>= 1) {
        t += __shfl_xor(t, off);
        c += __shfl_xor(c, off);
    }
    if (lane == 0) {
        if (c < 1.0f) c = 1.0f;
        out[0] = t / c;
    }
}

extern "C" void kernel_launch(void* const* d_in, const int* in_sizes, int n_in,
                              void* d_out, int out_size, void* d_ws, size_t ws_size,
                              hipStream_t stream)
{
    const float* a      = (const float*)d_in[0];
    const float* b      = (const float*)d_in[1];
    const int*   labels = (const int*)d_in[2];
    const int N = in_sizes[2];

    float2* partials = (float2*)d_ws;

    cosloss_main<<<1024, 512, 0, stream>>>(a, b, labels, N, partials);
    cosloss_final<<<1, 64, 0, stream>>>((const float4*)partials, (float*)d_out);
}